// Round 15
// baseline (12078.481 us; speedup 1.0000x reference)
//
#include <hip/hip_runtime.h>

// CharRNN: 3-layer shared-weight LSTM (H=65) over T=4096, B=50, + dense head.
//
// Round-15: R11's FUSED one-barrier structure with R9's PROVEN register
// spelling. 8-lane group per cell n; lane j = (side, k-quarter q). Thread owns
// the cell's 4 gate columns x 16 rows (64 floats in 16 float4 + 4 tail
// scalars), loops all 3 layers. 12 DPP adds -> every lane holds the 4 full
// z's -> activation + c + h in-register; lane j==0 publishes h (1 ds_write).
// No s_z, no Phase B, ONE barrier/round, parity-double-buffered h/x.
//   R11 failed on spill (VGPR 56) from v2f component-KEEP; R9's float4+KEEP4
//   granted 88 with no spill. R14 proved pk fp32 is half-rate on gfx950
//   (peak 157 TF = scalar rate) -> scalar fmaf everywhere.

#define HH    65
#define G4    260
#define TT    4096
#define NB    50
#define BLOCK 640
#define NMAIN 520
#define DROWS 64

#define KEEP4(v) asm volatile("" : "+v"(v.x), "+v"(v.y), "+v"(v.z), "+v"(v.w))
#define KEEP(s)  asm volatile("" : "+v"(s))

__device__ __forceinline__ float sigm(float x)  { return 1.0f / (1.0f + __expf(-x)); }
__device__ __forceinline__ float tanha(float x) { float e = __expf(2.0f * x); return 1.0f - 2.0f / (e + 1.0f); }

// sum across 8-lane group (lane bits 0-2): quad xor1, quad xor2, row_half_mirror
__device__ __forceinline__ float qsum8(float v) {
    int i = __float_as_int(v);
    v += __int_as_float(__builtin_amdgcn_update_dpp(0, i, 0xB1,  0xF, 0xF, true));
    i = __float_as_int(v);
    v += __int_as_float(__builtin_amdgcn_update_dpp(0, i, 0x4E,  0xF, 0xF, true));
    i = __float_as_int(v);
    v += __int_as_float(__builtin_amdgcn_update_dpp(0, i, 0x141, 0xF, 0xF, true));
    return v;
}

__global__ void __launch_bounds__(BLOCK)
__attribute__((amdgpu_waves_per_eu(2, 3)))
charrnn_rec(const float* __restrict__ x, const float* __restrict__ W,
            const float* __restrict__ U, const float* __restrict__ bv,
            float* __restrict__ out)
{
    __shared__ __align__(16) float s_h[3][2][68];  // [layer][parity][cell]
    __shared__ __align__(16) float s_x[2][68];     // x(t) staging, parity-buffered

    const int bat = blockIdx.x, tid = threadIdx.x;
    const float* xb   = x   + (size_t)bat * TT * HH;
    float*       outb = out + (size_t)bat * TT * HH;

    for (int i = tid; i < 3 * 2 * 68; i += BLOCK) (&s_h[0][0][0])[i] = 0.0f;
    for (int i = tid; i < 2 * 68; i += BLOCK)     (&s_x[0][0])[i] = 0.0f;

    const bool isM  = (tid < NMAIN);
    const int  n    = tid >> 3;          // cell 0..64 (main threads)
    const int  j    = tid & 7;
    const int  side = j >> 2;            // 0 = input side (x / h[l-1]), 1 = recurrent side
    const int  q    = j & 3;             // rows 16q..16q+15 (+row 64 if q==3)
    const int  kst  = 16 * q;
    const float* M  = side ? U : W;

    // 4 gate cols x 16 rows: 16 float4 (R9-proven spelling) + 4 tail scalars
    float4 wa0, wa1, wa2, wa3, wb0, wb1, wb2, wb3,
           wc0, wc1, wc2, wc3, wd0, wd1, wd2, wd3;
#define WLD(v, g, k4)                                                         \
    do {                                                                      \
        v.x = isM ? M[(kst + 4 * (k4) + 0) * G4 + n + 65 * (g)] : 0.0f;       \
        v.y = isM ? M[(kst + 4 * (k4) + 1) * G4 + n + 65 * (g)] : 0.0f;       \
        v.z = isM ? M[(kst + 4 * (k4) + 2) * G4 + n + 65 * (g)] : 0.0f;       \
        v.w = isM ? M[(kst + 4 * (k4) + 3) * G4 + n + 65 * (g)] : 0.0f;       \
        KEEP4(v);                                                             \
    } while (0)
    WLD(wa0, 0, 0); WLD(wa1, 0, 1); WLD(wa2, 0, 2); WLD(wa3, 0, 3);
    WLD(wb0, 1, 0); WLD(wb1, 1, 1); WLD(wb2, 1, 2); WLD(wb3, 1, 3);
    WLD(wc0, 2, 0); WLD(wc1, 2, 1); WLD(wc2, 2, 2); WLD(wc3, 2, 3);
    WLD(wd0, 3, 0); WLD(wd1, 3, 1); WLD(wd2, 3, 2); WLD(wd3, 3, 3);
#undef WLD
    const bool hasT = isM && (q == 3);
    float wsA = hasT ? M[64 * G4 + n]       : 0.0f; KEEP(wsA);
    float wsB = hasT ? M[64 * G4 + n + 65]  : 0.0f; KEEP(wsB);
    float wsC = hasT ? M[64 * G4 + n + 130] : 0.0f; KEEP(wsC);
    float wsD = hasT ? M[64 * G4 + n + 195] : 0.0f; KEEP(wsD);

    const float bz0 = isM ? bv[n]       : 0.0f;
    const float bz1 = isM ? bv[65 + n]  : 0.0f;
    const float bz2 = isM ? bv[130 + n] : 0.0f;
    const float bz3 = isM ? bv[195 + n] : 0.0f;

    // x prefetch: tids 576..639 -> pidx 0..63; tid 520 -> pidx 64
    const int pidx = (tid >= 576) ? (tid - 576) : ((tid == NMAIN) ? 64 : -1);
    float cur = 0.0f, nxt = 0.0f;
    if (pidx >= 0) {
        s_x[0][pidx] = xb[pidx];        // x(0)
        cur = xb[HH + pidx];            // x(1)
    }

    float creg0 = 0.0f, creg1 = 0.0f, creg2 = 0.0f;
    int p = 0;
    __syncthreads();

    for (int r = 0; r < TT + 2; ++r) {
        if (pidx >= 0) {   // issue x(r+2) early; latency hidden under FMAs
            const int tn = r + 2;
            nxt = (tn < TT) ? xb[(size_t)tn * HH + pidx] : 0.0f;
        }
        if (isM) {
#pragma unroll
            for (int l = 0; l < 3; ++l) {
                if ((unsigned)(r - l) < TT) {
                    const float* hb = side ? &s_h[l][p][0]
                                           : (l == 0 ? &s_x[p][0] : &s_h[l - 1][p][0]);
                    const float4* h4 = (const float4*)(hb + kst);   // 16B aligned
                    const float4 H0 = h4[0], H1 = h4[1], H2 = h4[2], H3 = h4[3];
                    const float  h64 = hb[64];
                    float a0, a1, a2, a3;
#define CD(acc, p0, p1, p2, p3, ps)                                           \
    {   float u0, u1;                                                         \
        u0 = H0.x * p0.x;           u1 = H0.y * p0.y;                         \
        u0 = fmaf(H0.z, p0.z, u0);  u1 = fmaf(H0.w, p0.w, u1);                \
        u0 = fmaf(H1.x, p1.x, u0);  u1 = fmaf(H1.y, p1.y, u1);                \
        u0 = fmaf(H1.z, p1.z, u0);  u1 = fmaf(H1.w, p1.w, u1);                \
        u0 = fmaf(H2.x, p2.x, u0);  u1 = fmaf(H2.y, p2.y, u1);                \
        u0 = fmaf(H2.z, p2.z, u0);  u1 = fmaf(H2.w, p2.w, u1);                \
        u0 = fmaf(H3.x, p3.x, u0);  u1 = fmaf(H3.y, p3.y, u1);                \
        u0 = fmaf(H3.z, p3.z, u0);  u1 = fmaf(H3.w, p3.w, u1);                \
        u0 = fmaf(h64, ps, u0);                                               \
        acc = u0 + u1; }
                    CD(a0, wa0, wa1, wa2, wa3, wsA)
                    CD(a1, wb0, wb1, wb2, wb3, wsB)
                    CD(a2, wc0, wc1, wc2, wc3, wsC)
                    CD(a3, wd0, wd1, wd2, wd3, wsD)
#undef CD
                    const float z0 = qsum8(a0) + bz0;
                    const float z1 = qsum8(a1) + bz1;
                    const float z2 = qsum8(a2) + bz2;
                    const float z3 = qsum8(a3) + bz3;
                    const float ig = sigm(z0), fg = sigm(z1),
                                gg = tanha(z2), og = sigm(z3);
                    float c;
                    if (l == 0)      { creg0 = fmaf(fg, creg0, ig * gg); c = creg0; }
                    else if (l == 1) { creg1 = fmaf(fg, creg1, ig * gg); c = creg1; }
                    else             { creg2 = fmaf(fg, creg2, ig * gg); c = creg2; }
                    const float h = og * tanha(c);
                    if (j == 0) {
                        s_h[l][p ^ 1][n] = h;
                        if (l == 2) outb[(size_t)(r - 2) * HH + n] = h;
                    }
                }
            }
        }
        if (pidx >= 0) {
            if (r + 1 < TT) s_x[p ^ 1][pidx] = cur;
            cur = nxt;
        }
        __syncthreads();
        p ^= 1;
    }
}

// ---- kernel 2: in-place dense head over d_out: y = h2 @ Wd + bd ----
__global__ void __launch_bounds__(256, 1)
dense_head(float* __restrict__ io, const float* __restrict__ Wd, const float* __restrict__ bd)
{
    __shared__ __align__(16) float s_h[DROWS][68];
    __shared__ float s_wd[HH][HH];
    __shared__ float s_bd[HH];

    const int tid = threadIdx.x;
    float* base = io + (size_t)blockIdx.x * DROWS * HH;

    for (int i = tid; i < DROWS * HH; i += 256) {
        const int row = i / HH, k = i - row * HH;
        s_h[row][k] = base[i];
    }
    for (int i = tid; i < HH * HH; i += 256) (&s_wd[0][0])[i] = Wd[i];
    if (tid < HH) s_bd[tid] = bd[tid];
    __syncthreads();

    for (int u = tid; u < DROWS * HH; u += 256) {
        const int row = u / HH, c = u - row * HH;
        const float4* hp = (const float4*)&s_h[row][0];
        float acc = s_bd[c];
#pragma unroll
        for (int k4 = 0; k4 < 16; ++k4) {
            const float4 hv = hp[k4];
            acc = fmaf(hv.x, s_wd[4 * k4 + 0][c], acc);
            acc = fmaf(hv.y, s_wd[4 * k4 + 1][c], acc);
            acc = fmaf(hv.z, s_wd[4 * k4 + 2][c], acc);
            acc = fmaf(hv.w, s_wd[4 * k4 + 3][c], acc);
        }
        acc = fmaf(s_h[row][64], s_wd[64][c], acc);
        base[u] = acc;   // safe: all reads come from LDS copies
    }
}

extern "C" void kernel_launch(void* const* d_in, const int* in_sizes, int n_in,
                              void* d_out, int out_size, void* d_ws, size_t ws_size,
                              hipStream_t stream)
{
    const float* x  = (const float*)d_in[0];
    const float* W  = (const float*)d_in[1];
    const float* U  = (const float*)d_in[2];
    const float* bv = (const float*)d_in[3];
    const float* Wd = (const float*)d_in[4];
    const float* bd = (const float*)d_in[5];
    float* out = (float*)d_out;

    hipLaunchKernelGGL(charrnn_rec, dim3(NB), dim3(BLOCK), 0, stream, x, W, U, bv, out);
    hipLaunchKernelGGL(dense_head, dim3(NB * TT / DROWS), dim3(256), 0, stream, out, Wd, bd);
}

// Round 16
// 6143.440 us; speedup vs baseline: 1.9661x; 1.9661x over previous
//
#include <hip/hip_runtime.h>

// CharRNN: 3-layer shared-weight LSTM (H=65) over T=4096, B=50, + dense head.
//
// Round-16: R9 structure with the SIMD-0 hotspot rebalanced.
//   R9's extra cols 256..259 ran on tids 0-15 & 256-271 = waves 0 AND 4,
//   which both map to SIMD 0 (wave i -> SIMD i%4): +870 cyc/round on one
//   SIMD while barrier-synced peers idle. Now EVERY wave owns one extra
//   column-dot on its lane-quad 56..59 (w=lane&3 covers rows 0..63 + row64
//   tail, reusing the staged H regs -> zero extra LDS), 2-DPP quad reduce,
//   lane w==0 publishes. +120 cyc/wave evenly vs +435 on two waves.
//   (R15: fused structure spills (VGPR 56) + 176M bank conflicts — dead.)

#define HH    65
#define G4    260
#define TT    4096
#define NB    50
#define BLOCK 512
#define DROWS 64

#define KEEP4(v) asm volatile("" : "+v"(v.x), "+v"(v.y), "+v"(v.z), "+v"(v.w))
#define KEEP(s)  asm volatile("" : "+v"(s))

__device__ __forceinline__ float sigm(float x)  { return 1.0f / (1.0f + __expf(-x)); }
__device__ __forceinline__ float tanha(float x) { float e = __expf(2.0f * x); return 1.0f - 2.0f / (e + 1.0f); }

// sum across the 4 lanes of a quad (lane bits 0-1) via DPP; all 4 lanes get total
__device__ __forceinline__ float qsum(float v) {
    int i = __float_as_int(v);
    v += __int_as_float(__builtin_amdgcn_update_dpp(0, i, 0xB1, 0xF, 0xF, true)); // [1,0,3,2]
    i = __float_as_int(v);
    v += __int_as_float(__builtin_amdgcn_update_dpp(0, i, 0x4E, 0xF, 0xF, true)); // [2,3,0,1]
    return v;
}

__global__ void __launch_bounds__(BLOCK)
__attribute__((amdgpu_waves_per_eu(2, 2)))
charrnn_rec(const float* __restrict__ x, const float* __restrict__ W,
            const float* __restrict__ U, const float* __restrict__ bv,
            float* __restrict__ out)
{
    __shared__ __align__(16) float s_hin[3][68];    // input to layer l (row0 = x(t)); [65..67]=0
    __shared__ __align__(16) float s_hrec[3][68];   // recurrent h per layer
    __shared__ __align__(16) float s_z[3][2][256];  // [layer][side][col] full dots, cols 0..255
    __shared__ float s_parte[3][2][4];              // [layer][side][col-256] dots, cols 256..259

    const int bat = blockIdx.x;
    const int tid = threadIdx.x;
    const float* xb   = x   + (size_t)bat * TT * HH;
    float*       outb = out + (size_t)bat * TT * HH;

    for (int i = tid; i < 3 * 68; i += BLOCK) { (&s_hin[0][0])[i] = 0.0f; (&s_hrec[0][0])[i] = 0.0f; }

    const int w    = tid & 3;             // k-window: rows 16w..16w+15 (+ row 64 on w==3)
    const int lane = tid & 63;
    const int wv   = tid >> 6;            // wave 0..7
    const int side = tid >> 8;            // 0 = W (reads hin), 1 = U (reads hrec)
    const int qL   = (tid >> 2) & 63;     // column quad within side
    const int col0 = qL * 4;              // cols col0..col0+3 (0..255)
    const float* M = side ? U : W;

    // 16 float4 weights (R9-proven spelling)
    float4 wa0, wa1, wa2, wa3, wb0, wb1, wb2, wb3,
           wc0, wc1, wc2, wc3, wd0, wd1, wd2, wd3;
#define WLD(v, c, q)                                                          \
    do {                                                                      \
        v.x = M[(16 * w + 4 * (q) + 0) * G4 + col0 + (c)];                    \
        v.y = M[(16 * w + 4 * (q) + 1) * G4 + col0 + (c)];                    \
        v.z = M[(16 * w + 4 * (q) + 2) * G4 + col0 + (c)];                    \
        v.w = M[(16 * w + 4 * (q) + 3) * G4 + col0 + (c)];                    \
        KEEP4(v);                                                             \
    } while (0)
    WLD(wa0, 0, 0); WLD(wa1, 0, 1); WLD(wa2, 0, 2); WLD(wa3, 0, 3);
    WLD(wb0, 1, 0); WLD(wb1, 1, 1); WLD(wb2, 1, 2); WLD(wb3, 1, 3);
    WLD(wc0, 2, 0); WLD(wc1, 2, 1); WLD(wc2, 2, 2); WLD(wc3, 2, 3);
    WLD(wd0, 3, 0); WLD(wd1, 3, 1); WLD(wd2, 3, 2); WLD(wd3, 3, 3);
#undef WLD
    float ws0 = (w == 3) ? M[64 * G4 + col0 + 0] : 0.0f; KEEP(ws0);
    float ws1 = (w == 3) ? M[64 * G4 + col0 + 1] : 0.0f; KEEP(ws1);
    float ws2 = (w == 3) ? M[64 * G4 + col0 + 2] : 0.0f; KEEP(ws2);
    float ws3 = (w == 3) ? M[64 * G4 + col0 + 3] : 0.0f; KEEP(ws3);

    // extra cols 256..259 REBALANCED: every wave's lane-quad 56..59 computes
    // one col (256 + (wv&3)) for its side, reusing its staged H window.
    const bool isE  = (lane >= 56) && (lane < 60);
    const int  colE = 256 + (wv & 3);
    float4 e0, e1, e2, e3;
#define ELD(v, q)                                                             \
    do {                                                                      \
        v.x = isE ? M[(16 * w + 4 * (q) + 0) * G4 + colE] : 0.0f;             \
        v.y = isE ? M[(16 * w + 4 * (q) + 1) * G4 + colE] : 0.0f;             \
        v.z = isE ? M[(16 * w + 4 * (q) + 2) * G4 + colE] : 0.0f;             \
        v.w = isE ? M[(16 * w + 4 * (q) + 3) * G4 + colE] : 0.0f;             \
        KEEP4(v);                                                             \
    } while (0)
    ELD(e0, 0); ELD(e1, 1); ELD(e2, 2); ELD(e3, 3);
#undef ELD
    float esc = (isE && w == 3) ? M[64 * G4 + colE] : 0.0f; KEEP(esc);

    // cell role (tid < 195): biases pre-loaded to registers
    const int  cl = tid / 65, n = tid - (tid / 65) * 65;
    const bool isC = (tid < 195);
    const float bz0 = bv[n], bz1 = bv[65 + n], bz2 = bv[130 + n], bz3 = bv[195 + n];
    float creg = 0.0f;

    // x prefetch: tids 447..511 -> pidx 0..64
    const bool isP  = (tid >= 447);
    const int  pidx = tid - 447;
    float cur = 0.0f, nxt = 0.0f;
    if (isP) {
        s_hin[0][pidx] = xb[pidx];      // x(0)
        cur = xb[HH + pidx];            // x(1)
    }
    __syncthreads();

    for (int r = 0; r < TT + 2; ++r) {
        // ---------------- Phase A ----------------
        if (isP) {  // issue x(r+2) early
            const int tn = r + 2;
            nxt = (tn < TT) ? xb[(size_t)tn * HH + pidx] : 0.0f;
        }
#pragma unroll
        for (int l = 0; l < 3; ++l) {
            if ((unsigned)(r - l) < TT) {
                const float* hb = side ? &s_hrec[l][0] : &s_hin[l][0];
                const float4* h4 = (const float4*)(hb + 16 * w);   // 16B aligned
                const float4 H0 = h4[0], H1 = h4[1], H2 = h4[2], H3 = h4[3];
                const float  h64 = hb[64];                          // broadcast b32
                float a0, a1, a2, a3;
#define COLDOT(acc, p0, p1, p2, p3, ps)                                       \
    {   float u0, u1;                                                         \
        u0 = H0.x * p0.x;           u1 = H0.y * p0.y;                         \
        u0 = fmaf(H0.z, p0.z, u0);  u1 = fmaf(H0.w, p0.w, u1);                \
        u0 = fmaf(H1.x, p1.x, u0);  u1 = fmaf(H1.y, p1.y, u1);                \
        u0 = fmaf(H1.z, p1.z, u0);  u1 = fmaf(H1.w, p1.w, u1);                \
        u0 = fmaf(H2.x, p2.x, u0);  u1 = fmaf(H2.y, p2.y, u1);                \
        u0 = fmaf(H2.z, p2.z, u0);  u1 = fmaf(H2.w, p2.w, u1);                \
        u0 = fmaf(H3.x, p3.x, u0);  u1 = fmaf(H3.y, p3.y, u1);                \
        u0 = fmaf(H3.z, p3.z, u0);  u1 = fmaf(H3.w, p3.w, u1);                \
        u0 = fmaf(h64, ps, u0);                                               \
        acc = u0 + u1; }
                COLDOT(a0, wa0, wa1, wa2, wa3, ws0)
                COLDOT(a1, wb0, wb1, wb2, wb3, ws1)
                COLDOT(a2, wc0, wc1, wc2, wc3, ws2)
                COLDOT(a3, wd0, wd1, wd2, wd3, ws3)
                a0 = qsum(a0); a1 = qsum(a1); a2 = qsum(a2); a3 = qsum(a3);
                if (w == 0)
                    *(float4*)&s_z[l][side][col0] = make_float4(a0, a1, a2, a3);
                if (isE) {
                    float ea;
                    COLDOT(ea, e0, e1, e2, e3, esc)
                    ea = qsum(ea);
                    if (w == 0) s_parte[l][side][wv & 3] = ea;
                }
#undef COLDOT
            }
        }
        __syncthreads();

        // ---------------- Phase B: cell updates ----------------
        if (isC) {
            if ((unsigned)(r - cl) < TT) {
                const float zi = bz0 + s_z[cl][0][n]       + s_z[cl][1][n];
                const float zf = bz1 + s_z[cl][0][65 + n]  + s_z[cl][1][65 + n];
                const float zg = bz2 + s_z[cl][0][130 + n] + s_z[cl][1][130 + n];
                float zo;
                if (n < 61) zo = bz3 + s_z[cl][0][195 + n]    + s_z[cl][1][195 + n];
                else        zo = bz3 + s_parte[cl][0][n - 61] + s_parte[cl][1][n - 61];
                const float ig = sigm(zi), fg = sigm(zf), gg = tanha(zg), og = sigm(zo);
                creg = fmaf(fg, creg, ig * gg);
                const float h = og * tanha(creg);
                s_hrec[cl][n] = h;
                if (cl < 2) s_hin[cl + 1][n] = h;
                else        outb[(size_t)(r - cl) * HH + n] = h;   // stream h2 to out
            }
        }
        if (isP) {
            if (r + 1 < TT) s_hin[0][pidx] = cur;
            cur = nxt;
        }
        __syncthreads();
    }
}

// ---- kernel 2: in-place dense head over d_out: y = h2 @ Wd + bd ----
__global__ void __launch_bounds__(256, 1)
dense_head(float* __restrict__ io, const float* __restrict__ Wd, const float* __restrict__ bd)
{
    __shared__ __align__(16) float s_h[DROWS][68];
    __shared__ float s_wd[HH][HH];
    __shared__ float s_bd[HH];

    const int tid = threadIdx.x;
    float* base = io + (size_t)blockIdx.x * DROWS * HH;

    for (int i = tid; i < DROWS * HH; i += 256) {
        const int row = i / HH, k = i - row * HH;
        s_h[row][k] = base[i];
    }
    for (int i = tid; i < HH * HH; i += 256) (&s_wd[0][0])[i] = Wd[i];
    if (tid < HH) s_bd[tid] = bd[tid];
    __syncthreads();

    for (int u = tid; u < DROWS * HH; u += 256) {
        const int row = u / HH, c = u - row * HH;
        const float4* hp = (const float4*)&s_h[row][0];
        float acc = s_bd[c];
#pragma unroll
        for (int k4 = 0; k4 < 16; ++k4) {
            const float4 hv = hp[k4];
            acc = fmaf(hv.x, s_wd[4 * k4 + 0][c], acc);
            acc = fmaf(hv.y, s_wd[4 * k4 + 1][c], acc);
            acc = fmaf(hv.z, s_wd[4 * k4 + 2][c], acc);
            acc = fmaf(hv.w, s_wd[4 * k4 + 3][c], acc);
        }
        acc = fmaf(s_h[row][64], s_wd[64][c], acc);
        base[u] = acc;   // safe: all reads come from LDS copies
    }
}

extern "C" void kernel_launch(void* const* d_in, const int* in_sizes, int n_in,
                              void* d_out, int out_size, void* d_ws, size_t ws_size,
                              hipStream_t stream)
{
    const float* x  = (const float*)d_in[0];
    const float* W  = (const float*)d_in[1];
    const float* U  = (const float*)d_in[2];
    const float* bv = (const float*)d_in[3];
    const float* Wd = (const float*)d_in[4];
    const float* bd = (const float*)d_in[5];
    float* out = (float*)d_out;

    hipLaunchKernelGGL(charrnn_rec, dim3(NB), dim3(BLOCK), 0, stream, x, W, U, bv, out);
    hipLaunchKernelGGL(dense_head, dim3(NB * TT / DROWS), dim3(256), 0, stream, out, Wd, bd);
}